// Round 3
// baseline (718.566 us; speedup 1.0000x reference)
//
#include <hip/hip_runtime.h>
#include <math.h>

// ---------------------------------------------------------------------------
// Stage 1: conv1(5x5,pad1) + ReLU + BN(eval) + maxpool(3,2,1, zero-pad)
//   in : x [512,3,128,128]   out: out1 [512,5,63,63]
//   w(o,c,ki,kj) = k1[((c*5+ki)*5+kj)*5 + o]   (reference reshape semantics)
// Two-phase: conv once into LDS (33x33 region), then pool 16x16 from LDS.
// Phase A: 231 threads own one conv row-segment of 5 consecutive x-pixels.
// ---------------------------------------------------------------------------
__global__ __launch_bounds__(256) void conv1_pool_kernel(
    const float* __restrict__ x, const float* __restrict__ k1,
    const float* __restrict__ gamma, const float* __restrict__ beta,
    float* __restrict__ out1)
{
    const int b    = blockIdx.y;
    const int tile = blockIdx.x;          // 0..15
    const int ty = tile >> 2, tx = tile & 3;
    const int tid = threadIdx.x;

    __shared__ float sIn[3][37][40];      // input tile (37x37 used, col-pad)
    __shared__ float sConv[5][33][34];    // post-BN conv values (33x33)

    const int iy0 = 32 * ty - 2, ix0 = 32 * tx - 2;
    for (int idx = tid; idx < 3 * 37 * 37; idx += 256) {
        int c  = idx / 1369;
        int r  = idx - c * 1369;
        int ly = r / 37, lx = r - ly * 37;
        int gy = iy0 + ly, gx = ix0 + lx;
        float v = 0.f;
        if ((unsigned)gy < 128u && (unsigned)gx < 128u)
            v = x[((b * 3 + c) * 128 + gy) * 128 + gx];
        sIn[c][ly][lx] = v;
    }
    __syncthreads();

    // ---- Phase A: conv 33x33 region, 5 px per thread (x-consecutive) ----
    if (tid < 231) {
        const int ly  = tid / 7;          // 0..32 conv row
        const int cg  = tid - 7 * ly;     // 0..6 col group
        const int lx0 = 5 * cg;           // 0,5,...,30
        const int cy  = 32 * ty - 1 + ly;
        const int cx0 = 32 * tx - 1 + lx0;

        float acc[5][5];
#pragma unroll
        for (int p = 0; p < 5; ++p)
#pragma unroll
            for (int o = 0; o < 5; ++o) acc[p][o] = 0.f;

#pragma unroll
        for (int c = 0; c < 3; ++c)
#pragma unroll
            for (int ki = 0; ki < 5; ++ki) {
                float iv[9];
#pragma unroll
                for (int j = 0; j < 9; ++j) iv[j] = sIn[c][ly + ki][lx0 + j];
#pragma unroll
                for (int kj = 0; kj < 5; ++kj) {
                    const float* w = &k1[((c * 5 + ki) * 5 + kj) * 5];
#pragma unroll
                    for (int p = 0; p < 5; ++p) {
                        float v = iv[p + kj];
#pragma unroll
                        for (int o = 0; o < 5; ++o)
                            acc[p][o] = fmaf(v, w[o], acc[p][o]);
                    }
                }
            }

        const float invs = rsqrtf(1.0f + 1e-5f);
        float sc[5], bt[5];
#pragma unroll
        for (int o = 0; o < 5; ++o) { sc[o] = gamma[o] * invs; bt[o] = beta[o]; }

        const bool rowok = (unsigned)cy < 126u;
#pragma unroll
        for (int p = 0; p < 5; ++p) {
            const int lx = lx0 + p;
            if (lx < 33) {
                const bool ok = rowok && ((unsigned)(cx0 + p) < 126u);
#pragma unroll
                for (int o = 0; o < 5; ++o) {
                    float v = fmaxf(acc[p][o], 0.f) * sc[o] + bt[o];
                    sConv[o][ly][lx] = ok ? v : 0.f;   // 0 = pool zero-pad
                }
            }
        }
    }
    __syncthreads();

    // ---- Phase B: 16x16 pool outputs from LDS ----
    const int lpy = tid >> 4, lpx = tid & 15;
    const int py = 16 * ty + lpy, px = 16 * tx + lpx;
    if (py < 63 && px < 63) {
#pragma unroll
        for (int o = 0; o < 5; ++o) {
            float m = -3.4e38f;
#pragma unroll
            for (int dy = 0; dy < 3; ++dy)
#pragma unroll
                for (int dx = 0; dx < 3; ++dx)
                    m = fmaxf(m, sConv[o][2 * lpy + dy][2 * lpx + dx]);
            out1[((b * 5 + o) * 63 + py) * 63 + px] = m;
        }
    }
}

// ---------------------------------------------------------------------------
// Stage 2: conv2(3x3,pad1) + ReLU + maxpool(3,2,1)
//   in : out1 [512,5,63,63]  out: out2 [512,9,32,32]
//   w(o,c,ki,kj) = k2[((c*3+ki)*3+kj)*9 + o]
// Same two-phase structure; conv grid 63x63, region 33x33 per tile.
// ---------------------------------------------------------------------------
__global__ __launch_bounds__(256) void conv2_pool_kernel(
    const float* __restrict__ in1, const float* __restrict__ k2,
    float* __restrict__ out2)
{
    const int b    = blockIdx.y;
    const int tile = blockIdx.x;          // 0..3
    const int ty = tile >> 1, tx = tile & 1;
    const int tid = threadIdx.x;

    __shared__ float sIn[5][35][38];      // input tile (35x35 used)
    __shared__ float sConv[9][33][34];    // post-relu conv values

    const int iy0 = 32 * ty - 2, ix0 = 32 * tx - 2;
    for (int idx = tid; idx < 5 * 35 * 35; idx += 256) {
        int c  = idx / 1225;
        int r  = idx - c * 1225;
        int ly = r / 35, lx = r - ly * 35;
        int gy = iy0 + ly, gx = ix0 + lx;
        float v = 0.f;
        if ((unsigned)gy < 63u && (unsigned)gx < 63u)
            v = in1[((b * 5 + c) * 63 + gy) * 63 + gx];
        sIn[c][ly][lx] = v;
    }
    __syncthreads();

    // ---- Phase A ----
    if (tid < 231) {
        const int ly  = tid / 7;
        const int cg  = tid - 7 * ly;
        const int lx0 = 5 * cg;
        const int cy  = 32 * ty - 1 + ly;
        const int cx0 = 32 * tx - 1 + lx0;

        float acc[5][9];
#pragma unroll
        for (int p = 0; p < 5; ++p)
#pragma unroll
            for (int o = 0; o < 9; ++o) acc[p][o] = 0.f;

#pragma unroll
        for (int c = 0; c < 5; ++c)
#pragma unroll
            for (int ki = 0; ki < 3; ++ki) {
                float iv[7];
#pragma unroll
                for (int j = 0; j < 7; ++j) iv[j] = sIn[c][ly + ki][lx0 + j];
#pragma unroll
                for (int kj = 0; kj < 3; ++kj) {
                    const float* w = &k2[((c * 3 + ki) * 3 + kj) * 9];
#pragma unroll
                    for (int p = 0; p < 5; ++p) {
                        float v = iv[p + kj];
#pragma unroll
                        for (int o = 0; o < 9; ++o)
                            acc[p][o] = fmaf(v, w[o], acc[p][o]);
                    }
                }
            }

        const bool rowok = (unsigned)cy < 63u;
#pragma unroll
        for (int p = 0; p < 5; ++p) {
            const int lx = lx0 + p;
            if (lx < 33) {
                const bool ok = rowok && ((unsigned)(cx0 + p) < 63u);
#pragma unroll
                for (int o = 0; o < 9; ++o)
                    sConv[o][ly][lx] = ok ? fmaxf(acc[p][o], 0.f) : 0.f;
            }
        }
    }
    __syncthreads();

    // ---- Phase B ----
    const int lpy = tid >> 4, lpx = tid & 15;
    const int py = 16 * ty + lpy, px = 16 * tx + lpx;   // always < 32
#pragma unroll
    for (int o = 0; o < 9; ++o) {
        float m = 0.f;                    // relu'd values, zero pool-pad
#pragma unroll
        for (int dy = 0; dy < 3; ++dy)
#pragma unroll
            for (int dx = 0; dx < 3; ++dx)
                m = fmaxf(m, sConv[o][2 * lpy + dy][2 * lpx + dx]);
        out2[((b * 9 + o) * 32 + py) * 32 + px] = m;
    }
}

// ---------------------------------------------------------------------------
// Stage 3: conv3(3x3,pad1) + flatten + FC(16384->6) + softmax, per sample.
//   1024 threads, one conv pixel each (16 waves -> 32 waves/CU occupancy).
//   w(o,c,ki,kj) = k3[((c*3+ki)*3+kj)*16 + o]
// ---------------------------------------------------------------------------
__global__ __launch_bounds__(1024) void conv3_fc_kernel(
    const float* __restrict__ in2, const float* __restrict__ k3,
    const float* __restrict__ fcw, const float* __restrict__ fcb,
    float* __restrict__ out)
{
    const int b   = blockIdx.x;
    const int tid = threadIdx.x;

    __shared__ float sP[9][34][36];   // zero-padded border
    __shared__ float sRed[16][6];

    for (int idx = tid; idx < 9 * 34 * 36; idx += 1024) {
        int c  = idx / (34 * 36);
        int r  = idx - c * (34 * 36);
        int yy = r / 36, xx = r - yy * 36;
        float v = 0.f;
        if (yy >= 1 && yy < 33 && xx >= 1 && xx < 33)
            v = in2[((b * 9 + c) * 32 + (yy - 1)) * 32 + (xx - 1)];
        sP[c][yy][xx] = v;
    }
    __syncthreads();

    const int s = tid;                 // spatial index 0..1023
    const int y = s >> 5, xc = s & 31;

    float acc16[16];
#pragma unroll
    for (int o = 0; o < 16; ++o) acc16[o] = 0.f;

#pragma unroll
    for (int c = 0; c < 9; ++c)
#pragma unroll
        for (int ki = 0; ki < 3; ++ki) {
            float iv[3];
#pragma unroll
            for (int j = 0; j < 3; ++j) iv[j] = sP[c][y + ki][xc + j];
#pragma unroll
            for (int kj = 0; kj < 3; ++kj) {
                float v = iv[kj];
                const float* w = &k3[((c * 3 + ki) * 3 + kj) * 16];
#pragma unroll
                for (int o = 0; o < 16; ++o)
                    acc16[o] = fmaf(v, w[o], acc16[o]);
            }
        }

    // FC contribution of this pixel's 16 conv3 outputs
    float acc6[6] = {0.f, 0.f, 0.f, 0.f, 0.f, 0.f};
#pragma unroll
    for (int o = 0; o < 16; ++o) {
        const int f = o * 1024 + s;
#pragma unroll
        for (int cls = 0; cls < 6; ++cls)
            acc6[cls] = fmaf(acc16[o], fcw[cls * 16384 + f], acc6[cls]);
    }

    // block reduction of 6 logits (16 waves)
#pragma unroll
    for (int cls = 0; cls < 6; ++cls) {
        float v = acc6[cls];
#pragma unroll
        for (int off = 32; off >= 1; off >>= 1)
            v += __shfl_xor(v, off, 64);
        if ((tid & 63) == 0) sRed[tid >> 6][cls] = v;
    }
    __syncthreads();
    if (tid == 0) {
        float logits[6], mxl = -3.4e38f;
#pragma unroll
        for (int cls = 0; cls < 6; ++cls) {
            float l = fcb[cls];
            for (int wv = 0; wv < 16; ++wv) l += sRed[wv][cls];
            logits[cls] = l;
            mxl = fmaxf(mxl, l);
        }
        float ssum = 0.f;
#pragma unroll
        for (int cls = 0; cls < 6; ++cls) {
            logits[cls] = expf(logits[cls] - mxl);
            ssum += logits[cls];
        }
#pragma unroll
        for (int cls = 0; cls < 6; ++cls)
            out[b * 6 + cls] = logits[cls] / ssum;
    }
}

extern "C" void kernel_launch(void* const* d_in, const int* in_sizes, int n_in,
                              void* d_out, int out_size, void* d_ws, size_t ws_size,
                              hipStream_t stream)
{
    const float* x     = (const float*)d_in[0];
    const float* k1    = (const float*)d_in[1];
    const float* gamma = (const float*)d_in[2];
    const float* beta  = (const float*)d_in[3];
    const float* k2    = (const float*)d_in[4];
    const float* k3    = (const float*)d_in[5];
    const float* fcw   = (const float*)d_in[6];
    const float* fcb   = (const float*)d_in[7];
    float* out = (float*)d_out;

    float* out1 = (float*)d_ws;                       // 512*5*63*63  (40.6 MB)
    float* out2 = out1 + (size_t)512 * 5 * 63 * 63;   // 512*9*32*32  (18.9 MB)

    conv1_pool_kernel<<<dim3(16, 512), 256, 0, stream>>>(x, k1, gamma, beta, out1);
    conv2_pool_kernel<<<dim3(4, 512), 256, 0, stream>>>(out1, k2, out2);
    conv3_fc_kernel<<<dim3(512), 1024, 0, stream>>>(out2, k3, fcw, fcb, out);
}

// Round 4
// 671.102 us; speedup vs baseline: 1.0707x; 1.0707x over previous
//
#include <hip/hip_runtime.h>
#include <math.h>

// ---------------------------------------------------------------------------
// Stage 1: conv1(5x5,pad1) + ReLU + BN(eval) + maxpool(3,2,1, zero-pad)
//   in : x [512,3,128,128]   out: out1 [512,5,63,63]
//   w(o,c,ki,kj) = k1[((c*5+ki)*5+kj)*5 + o]   (reference reshape semantics)
// Single-phase, register-blocked: each thread computes its 3x3 conv window
// in registers (acc[3][3][5]); per (c, input-row) one iv[7] LDS load feeds
// all dependent FMAs. LDS reads/thread: 147 (vs 675 in round-1).
// ---------------------------------------------------------------------------
__global__ __launch_bounds__(256) void conv1_pool_kernel(
    const float* __restrict__ x, const float* __restrict__ k1,
    const float* __restrict__ gamma, const float* __restrict__ beta,
    float* __restrict__ out1)
{
    const int b    = blockIdx.y;
    const int tile = blockIdx.x;          // 0..15
    const int ty = tile >> 2, tx = tile & 3;
    const int tid = threadIdx.x;

    __shared__ float sIn[3][37][40];      // 17.8 KB

    const int iy0 = 32 * ty - 2, ix0 = 32 * tx - 2;
    for (int idx = tid; idx < 3 * 37 * 37; idx += 256) {
        int c  = idx / 1369;
        int r  = idx - c * 1369;
        int ly = r / 37, lx = r - ly * 37;
        int gy = iy0 + ly, gx = ix0 + lx;
        float v = 0.f;
        if ((unsigned)gy < 128u && (unsigned)gx < 128u)
            v = x[((b * 3 + c) * 128 + gy) * 128 + gx];
        sIn[c][ly][lx] = v;
    }
    __syncthreads();

    const int lpy = tid >> 4, lpx = tid & 15;
    const int py = 16 * ty + lpy, px = 16 * tx + lpx;

    // conv rows cy0..cy0+2, cols cx0..cx0+2 (cy0=2py-1; row/col -1 masked later)
    float acc[3][3][5];
#pragma unroll
    for (int r = 0; r < 3; ++r)
#pragma unroll
        for (int p = 0; p < 3; ++p)
#pragma unroll
            for (int o = 0; o < 5; ++o) acc[r][p][o] = 0.f;

#pragma unroll
    for (int c = 0; c < 3; ++c)
#pragma unroll
        for (int ir = 0; ir < 7; ++ir) {
            float iv[7];
#pragma unroll
            for (int j = 0; j < 7; ++j)
                iv[j] = sIn[c][2 * lpy + ir][2 * lpx + j];
#pragma unroll
            for (int ki = 0; ki < 5; ++ki) {
                const int cr = ir - ki;            // compile-time per (ir,ki)
                if (cr >= 0 && cr < 3) {
#pragma unroll
                    for (int kj = 0; kj < 5; ++kj) {
                        const float* w = &k1[((c * 5 + ki) * 5 + kj) * 5];
#pragma unroll
                        for (int cp = 0; cp < 3; ++cp) {
                            float v = iv[cp + kj];
#pragma unroll
                            for (int o = 0; o < 5; ++o)
                                acc[cr][cp][o] = fmaf(v, w[o], acc[cr][cp][o]);
                        }
                    }
                }
            }
        }

    if (py < 63 && px < 63) {
        const float invs = rsqrtf(1.0f + 1e-5f);
        const bool tb = (py == 0), lb = (px == 0);
#pragma unroll
        for (int o = 0; o < 5; ++o) {
            const float sc = gamma[o] * invs, bt = beta[o];
            float m = -3.4e38f;
#pragma unroll
            for (int dy = 0; dy < 3; ++dy)
#pragma unroll
                for (int dx = 0; dx < 3; ++dx) {
                    float v = fmaf(fmaxf(acc[dy][dx][o], 0.f), sc, bt);
                    const bool ok = !(tb && dy == 0) && !(lb && dx == 0);
                    m = ok ? fmaxf(m, v) : m;
                }
            if (tb || lb) m = fmaxf(m, 0.f);      // pool zero-padding
            out1[((b * 5 + o) * 63 + py) * 63 + px] = m;
        }
    }
}

// ---------------------------------------------------------------------------
// Stage 2: conv2(3x3,pad1) + ReLU + maxpool(3,2,1)
//   in : out1 [512,5,63,63]  out: out2 [512,9,32,32]
//   w(o,c,ki,kj) = k2[((c*3+ki)*3+kj)*9 + o]
// Row-at-a-time register blocking: acc[3][9] per conv row; iv[5] per (c,ki)
// feeds 81 FMAs. Reads/thread: 225 (vs 405). relu+pool fold via m init 0.
// ---------------------------------------------------------------------------
__global__ __launch_bounds__(256) void conv2_pool_kernel(
    const float* __restrict__ in1, const float* __restrict__ k2,
    float* __restrict__ out2)
{
    const int b    = blockIdx.y;
    const int tile = blockIdx.x;          // 0..3
    const int ty = tile >> 1, tx = tile & 1;
    const int tid = threadIdx.x;

    __shared__ float sIn[5][35][38];      // 26.6 KB

    const int iy0 = 32 * ty - 2, ix0 = 32 * tx - 2;
    for (int idx = tid; idx < 5 * 35 * 35; idx += 256) {
        int c  = idx / 1225;
        int r  = idx - c * 1225;
        int ly = r / 35, lx = r - ly * 35;
        int gy = iy0 + ly, gx = ix0 + lx;
        float v = 0.f;
        if ((unsigned)gy < 63u && (unsigned)gx < 63u)
            v = in1[((b * 5 + c) * 63 + gy) * 63 + gx];
        sIn[c][ly][lx] = v;
    }
    __syncthreads();

    const int lpy = tid >> 4, lpx = tid & 15;
    const int py = 16 * ty + lpy, px = 16 * tx + lpx;   // 0..31

    float m[9];
#pragma unroll
    for (int o = 0; o < 9; ++o) m[o] = 0.f;   // relu>=0 and zero pool-pad

#pragma unroll
    for (int cr = 0; cr < 3; ++cr) {
        const int cy = 2 * py - 1 + cr;
        if ((unsigned)cy < 63u) {
            float acc[3][9];
#pragma unroll
            for (int p = 0; p < 3; ++p)
#pragma unroll
                for (int o = 0; o < 9; ++o) acc[p][o] = 0.f;

#pragma unroll
            for (int c = 0; c < 5; ++c)
#pragma unroll
                for (int ki = 0; ki < 3; ++ki) {
                    float iv[5];
#pragma unroll
                    for (int j = 0; j < 5; ++j)
                        iv[j] = sIn[c][2 * lpy + cr + ki][2 * lpx + j];
#pragma unroll
                    for (int kj = 0; kj < 3; ++kj) {
                        const float* w = &k2[((c * 3 + ki) * 3 + kj) * 9];
#pragma unroll
                        for (int cp = 0; cp < 3; ++cp) {
                            float v = iv[cp + kj];
#pragma unroll
                            for (int o = 0; o < 9; ++o)
                                acc[cp][o] = fmaf(v, w[o], acc[cp][o]);
                        }
                    }
                }

#pragma unroll
            for (int cp = 0; cp < 3; ++cp) {
                const int cx = 2 * px - 1 + cp;
                if ((unsigned)cx < 63u) {
#pragma unroll
                    for (int o = 0; o < 9; ++o)
                        m[o] = fmaxf(m[o], acc[cp][o]);
                }
            }
        }
    }

#pragma unroll
    for (int o = 0; o < 9; ++o)
        out2[((b * 9 + o) * 32 + py) * 32 + px] = m[o];
}

// ---------------------------------------------------------------------------
// Stage 3: conv3(3x3,pad1) + flatten + FC(16384->6) + softmax, per sample.
//   1024 threads, one conv pixel each.
//   w(o,c,ki,kj) = k3[((c*3+ki)*3+kj)*16 + o]
// ---------------------------------------------------------------------------
__global__ __launch_bounds__(1024) void conv3_fc_kernel(
    const float* __restrict__ in2, const float* __restrict__ k3,
    const float* __restrict__ fcw, const float* __restrict__ fcb,
    float* __restrict__ out)
{
    const int b   = blockIdx.x;
    const int tid = threadIdx.x;

    __shared__ float sP[9][34][36];   // zero-padded border
    __shared__ float sRed[16][6];

    for (int idx = tid; idx < 9 * 34 * 36; idx += 1024) {
        int c  = idx / (34 * 36);
        int r  = idx - c * (34 * 36);
        int yy = r / 36, xx = r - yy * 36;
        float v = 0.f;
        if (yy >= 1 && yy < 33 && xx >= 1 && xx < 33)
            v = in2[((b * 9 + c) * 32 + (yy - 1)) * 32 + (xx - 1)];
        sP[c][yy][xx] = v;
    }
    __syncthreads();

    const int s = tid;                 // spatial index 0..1023
    const int y = s >> 5, xc = s & 31;

    float acc16[16];
#pragma unroll
    for (int o = 0; o < 16; ++o) acc16[o] = 0.f;

#pragma unroll
    for (int c = 0; c < 9; ++c)
#pragma unroll
        for (int ki = 0; ki < 3; ++ki) {
            float iv[3];
#pragma unroll
            for (int j = 0; j < 3; ++j) iv[j] = sP[c][y + ki][xc + j];
#pragma unroll
            for (int kj = 0; kj < 3; ++kj) {
                float v = iv[kj];
                const float* w = &k3[((c * 3 + ki) * 3 + kj) * 16];
#pragma unroll
                for (int o = 0; o < 16; ++o)
                    acc16[o] = fmaf(v, w[o], acc16[o]);
            }
        }

    // FC contribution of this pixel's 16 conv3 outputs
    float acc6[6] = {0.f, 0.f, 0.f, 0.f, 0.f, 0.f};
#pragma unroll
    for (int o = 0; o < 16; ++o) {
        const int f = o * 1024 + s;
#pragma unroll
        for (int cls = 0; cls < 6; ++cls)
            acc6[cls] = fmaf(acc16[o], fcw[cls * 16384 + f], acc6[cls]);
    }

    // block reduction of 6 logits (16 waves)
#pragma unroll
    for (int cls = 0; cls < 6; ++cls) {
        float v = acc6[cls];
#pragma unroll
        for (int off = 32; off >= 1; off >>= 1)
            v += __shfl_xor(v, off, 64);
        if ((tid & 63) == 0) sRed[tid >> 6][cls] = v;
    }
    __syncthreads();
    if (tid == 0) {
        float logits[6], mxl = -3.4e38f;
#pragma unroll
        for (int cls = 0; cls < 6; ++cls) {
            float l = fcb[cls];
            for (int wv = 0; wv < 16; ++wv) l += sRed[wv][cls];
            logits[cls] = l;
            mxl = fmaxf(mxl, l);
        }
        float ssum = 0.f;
#pragma unroll
        for (int cls = 0; cls < 6; ++cls) {
            logits[cls] = expf(logits[cls] - mxl);
            ssum += logits[cls];
        }
#pragma unroll
        for (int cls = 0; cls < 6; ++cls)
            out[b * 6 + cls] = logits[cls] / ssum;
    }
}

extern "C" void kernel_launch(void* const* d_in, const int* in_sizes, int n_in,
                              void* d_out, int out_size, void* d_ws, size_t ws_size,
                              hipStream_t stream)
{
    const float* x     = (const float*)d_in[0];
    const float* k1    = (const float*)d_in[1];
    const float* gamma = (const float*)d_in[2];
    const float* beta  = (const float*)d_in[3];
    const float* k2    = (const float*)d_in[4];
    const float* k3    = (const float*)d_in[5];
    const float* fcw   = (const float*)d_in[6];
    const float* fcb   = (const float*)d_in[7];
    float* out = (float*)d_out;

    float* out1 = (float*)d_ws;                       // 512*5*63*63  (40.6 MB)
    float* out2 = out1 + (size_t)512 * 5 * 63 * 63;   // 512*9*32*32  (18.9 MB)

    conv1_pool_kernel<<<dim3(16, 512), 256, 0, stream>>>(x, k1, gamma, beta, out1);
    conv2_pool_kernel<<<dim3(4, 512), 256, 0, stream>>>(out1, k2, out2);
    conv3_fc_kernel<<<dim3(512), 1024, 0, stream>>>(out2, k3, fcw, fcb, out);
}

// Round 5
// 636.034 us; speedup vs baseline: 1.1298x; 1.0551x over previous
//
#include <hip/hip_runtime.h>
#include <math.h>

// ===========================================================================
// Stage 1: conv1(5x5,pad1) + ReLU + BN(eval) + maxpool(3,2,1, zero-pad)
//   in : x [512,3,128,128]   out: out1 [512,5,63,63]
//   w(o,c,ki,kj) = k1[((c*5+ki)*5+kj)*5 + o]   (reference reshape semantics)
// Exclusive-2x2 scheme: thread (lpy,lpx) computes conv rows {2py,2py+1} x
// cols {2px,2px+1} ONLY (1500 FMA, the true minimum). Pool(py,px) needs row
// 2py-1 / col 2px-1 -> fetched via LDS exchange (neighbors' values, aliased
// over the dead input tile) + a 65-px halo ring computed by threads 0..129.
// ===========================================================================

template<int O0, int NO>
__device__ __forceinline__ void conv1_halo(
    const float (*sIn)[37][38], const float* __restrict__ k1,
    const float* __restrict__ gamma, const float* __restrict__ beta,
    float invs, int ryh, int rxh, bool ok, float (*sH)[65], int idx)
{
    float ah[NO];
#pragma unroll
    for (int q = 0; q < NO; ++q) ah[q] = 0.f;
#pragma unroll
    for (int c = 0; c < 3; ++c)
#pragma unroll
        for (int ki = 0; ki < 5; ++ki) {
            float ivh[5];
#pragma unroll
            for (int kj = 0; kj < 5; ++kj)
                ivh[kj] = sIn[c][ryh + ki + 1][rxh + 1 + kj];
#pragma unroll
            for (int kj = 0; kj < 5; ++kj) {
                const float* w = &k1[((c * 5 + ki) * 5 + kj) * 5 + O0];
#pragma unroll
                for (int q = 0; q < NO; ++q)
                    ah[q] = fmaf(ivh[kj], w[q], ah[q]);
            }
        }
#pragma unroll
    for (int q = 0; q < NO; ++q) {
        float v = fmaf(fmaxf(ah[q], 0.f), gamma[O0 + q] * invs, beta[O0 + q]);
        sH[O0 + q][idx] = ok ? v : 0.f;
    }
}

__global__ __launch_bounds__(256) void conv1_pool_kernel(
    const float* __restrict__ x, const float* __restrict__ k1,
    const float* __restrict__ gamma, const float* __restrict__ beta,
    float* __restrict__ out1)
{
    const int b    = blockIdx.y;
    const int tile = blockIdx.x;          // 0..15
    const int ty = tile >> 2, tx = tile & 3;
    const int tid = threadIdx.x;

    __shared__ float smem[3 * 37 * 38];   // input tile; later aliased: exchange
    __shared__ float sH[5][65];           // halo ring (top 33 + left 32)
    float (*sIn)[37][38] = (float(*)[37][38])smem;

    const int iy0 = 32 * ty - 2, ix0 = 32 * tx - 2;
    for (int idx = tid; idx < 3 * 37 * 37; idx += 256) {
        int c  = idx / 1369;
        int r  = idx - c * 1369;
        int ly = r / 37, lx = r - ly * 37;
        int gy = iy0 + ly, gx = ix0 + lx;
        float v = 0.f;
        if ((unsigned)gy < 128u && (unsigned)gx < 128u)
            v = x[((b * 3 + c) * 128 + gy) * 128 + gx];
        sIn[c][ly][lx] = v;
    }
    __syncthreads();

    const int lpy = tid >> 4, lpx = tid & 15;
    const int py = 16 * ty + lpy, px = 16 * tx + lpx;
    const float invs = rsqrtf(1.0f + 1e-5f);

    // ---- exclusive 2x2 conv patch, all 5 channels ----
    float acc[2][2][5];
#pragma unroll
    for (int r = 0; r < 2; ++r)
#pragma unroll
        for (int p = 0; p < 2; ++p)
#pragma unroll
            for (int o = 0; o < 5; ++o) acc[r][p][o] = 0.f;

#pragma unroll
    for (int c = 0; c < 3; ++c)
#pragma unroll
        for (int lo = 1; lo <= 6; ++lo) {       // input row = 2lpy + lo
            float iv[6];
#pragma unroll
            for (int j = 0; j < 6; ++j)
                iv[j] = sIn[c][2 * lpy + lo][2 * lpx + 1 + j];
#pragma unroll
            for (int r = 0; r < 2; ++r) {
                const int ki = lo - 1 - r;      // compile-time
                if (ki >= 0 && ki < 5) {
#pragma unroll
                    for (int kj = 0; kj < 5; ++kj) {
                        const float* w = &k1[((c * 5 + ki) * 5 + kj) * 5];
#pragma unroll
                        for (int p = 0; p < 2; ++p) {
                            float v = iv[p + kj];
#pragma unroll
                            for (int o = 0; o < 5; ++o)
                                acc[r][p][o] = fmaf(v, w[o], acc[r][p][o]);
                        }
                    }
                }
            }
        }

    // ---- relu -> BN in place ----
#pragma unroll
    for (int o = 0; o < 5; ++o) {
        const float sc = gamma[o] * invs, bt = beta[o];
#pragma unroll
        for (int r = 0; r < 2; ++r)
#pragma unroll
            for (int p = 0; p < 2; ++p)
                acc[r][p][o] = fmaf(fmaxf(acc[r][p][o], 0.f), sc, bt);
    }

    // ---- halo ring: 65 px (top row 33 + left col 32), ch split 3/2 ----
    if (tid < 130) {
        const int idx = (tid < 65) ? tid : tid - 65;
        int ryh, rxh;
        if (idx < 33) { ryh = -1; rxh = idx - 1; }
        else          { ryh = idx - 33; rxh = -1; }
        const int cy = 32 * ty + ryh, cx = 32 * tx + rxh;
        const bool ok = (unsigned)cy < 126u && (unsigned)cx < 126u;
        if (tid < 65) conv1_halo<0, 3>(sIn, k1, gamma, beta, invs, ryh, rxh, ok, sH, idx);
        else          conv1_halo<3, 2>(sIn, k1, gamma, beta, invs, ryh, rxh, ok, sH, idx);
    }

    __syncthreads();                       // sIn reads complete -> alias ok

    // ---- exchange (aliased over smem): e0=v[0][1], e1=v[1][1], b=rowmax1 ----
    float* sE0 = smem;                     // [5][256]
    float* sE1 = smem + 5 * 256;
    float* sB  = smem + 10 * 256;
#pragma unroll
    for (int o = 0; o < 5; ++o) {
        sE0[o * 256 + tid] = acc[0][1][o];
        sE1[o * 256 + tid] = acc[1][1][o];
        sB [o * 256 + tid] = fmaxf(acc[1][0][o], acc[1][1][o]);
    }
    __syncthreads();

    // ---- pool from own regs + exchange + halo ----
    if (py < 63 && px < 63) {
        const int tU  = (lpy > 0) ? tid - 16 : 0;
        const int tL  = (lpx > 0) ? tid - 1  : 0;
        const int tUL = (lpy > 0 && lpx > 0) ? tid - 17 : 0;
#pragma unroll
        for (int o = 0; o < 5; ++o) {
            float a0 = fmaxf(acc[0][0][o], acc[0][1][o]);
            float a1 = fmaxf(acc[1][0][o], acc[1][1][o]);
            float u  = (lpy > 0) ? sB[o * 256 + tU]
                                 : fmaxf(sH[o][1 + 2 * lpx], sH[o][2 + 2 * lpx]);
            float l0 = (lpx > 0) ? sE0[o * 256 + tL] : sH[o][33 + 2 * lpy];
            float l1 = (lpx > 0) ? sE1[o * 256 + tL] : sH[o][34 + 2 * lpy];
            float ul = (lpy > 0 && lpx > 0) ? sE1[o * 256 + tUL]
                     : ((lpy == 0) ? sH[o][2 * lpx] : sH[o][32 + 2 * lpy]);
            float m = fmaxf(fmaxf(fmaxf(a0, a1), fmaxf(u, l0)), fmaxf(l1, ul));
            if (py == 0 || px == 0) m = fmaxf(m, 0.f);   // pool zero-pad
            out1[((b * 5 + o) * 63 + py) * 63 + px] = m;
        }
    }
}

// ===========================================================================
// Stage 2: conv2(3x3,pad1) + ReLU + maxpool(3,2,1)
//   in : out1 [512,5,63,63]  out: out2 [512,9,32,32]
//   w(o,c,ki,kj) = k2[((c*3+ki)*3+kj)*9 + o]
// Same exclusive-2x2 + exchange scheme. conv2 out is 63x63, so abs row/col 63
// (reached by py==31/px==31 patches) is pool zero-pad: post-relu values are
// >=0, so forcing those slots to 0 implements the pad exactly.
// Exchange done in 2 channel passes (5+4) to fit the aliased region.
// ===========================================================================

template<int O0, int NO>
__device__ __forceinline__ void conv2_halo(
    const float (*sIn)[35][36], const float* __restrict__ k2,
    int ryh, int rxh, bool ok, float (*sH)[65], int idx)
{
    float ah[NO];
#pragma unroll
    for (int q = 0; q < NO; ++q) ah[q] = 0.f;
#pragma unroll
    for (int c = 0; c < 5; ++c)
#pragma unroll
        for (int ki = 0; ki < 3; ++ki) {
            float ivh[3];
#pragma unroll
            for (int kj = 0; kj < 3; ++kj)
                ivh[kj] = sIn[c][ryh + ki + 1][rxh + 1 + kj];
#pragma unroll
            for (int kj = 0; kj < 3; ++kj) {
                const float* w = &k2[((c * 3 + ki) * 3 + kj) * 9 + O0];
#pragma unroll
                for (int q = 0; q < NO; ++q)
                    ah[q] = fmaf(ivh[kj], w[q], ah[q]);
            }
        }
#pragma unroll
    for (int q = 0; q < NO; ++q)
        sH[O0 + q][idx] = ok ? fmaxf(ah[q], 0.f) : 0.f;
}

__global__ __launch_bounds__(256) void conv2_pool_kernel(
    const float* __restrict__ in1, const float* __restrict__ k2,
    float* __restrict__ out2)
{
    const int b    = blockIdx.y;
    const int tile = blockIdx.x;          // 0..3
    const int ty = tile >> 1, tx = tile & 1;
    const int tid = threadIdx.x;

    __shared__ float smem[5 * 35 * 36];   // input tile; later aliased: exchange
    __shared__ float sH[9][65];
    float (*sIn)[35][36] = (float(*)[35][36])smem;

    const int iy0 = 32 * ty - 2, ix0 = 32 * tx - 2;
    for (int idx = tid; idx < 5 * 35 * 35; idx += 256) {
        int c  = idx / 1225;
        int r  = idx - c * 1225;
        int ly = r / 35, lx = r - ly * 35;
        int gy = iy0 + ly, gx = ix0 + lx;
        float v = 0.f;
        if ((unsigned)gy < 63u && (unsigned)gx < 63u)
            v = in1[((b * 5 + c) * 63 + gy) * 63 + gx];
        sIn[c][ly][lx] = v;
    }
    __syncthreads();

    const int lpy = tid >> 4, lpx = tid & 15;
    const int py = 16 * ty + lpy, px = 16 * tx + lpx;   // 0..31, all valid

    // ---- exclusive 2x2 conv patch, all 9 channels ----
    float acc[2][2][9];
#pragma unroll
    for (int r = 0; r < 2; ++r)
#pragma unroll
        for (int p = 0; p < 2; ++p)
#pragma unroll
            for (int o = 0; o < 9; ++o) acc[r][p][o] = 0.f;

#pragma unroll
    for (int c = 0; c < 5; ++c)
#pragma unroll
        for (int lo = 1; lo <= 4; ++lo) {       // input row = 2lpy + lo
            float iv[4];
#pragma unroll
            for (int j = 0; j < 4; ++j)
                iv[j] = sIn[c][2 * lpy + lo][2 * lpx + 1 + j];
#pragma unroll
            for (int r = 0; r < 2; ++r) {
                const int ki = lo - 1 - r;      // compile-time
                if (ki >= 0 && ki < 3) {
#pragma unroll
                    for (int kj = 0; kj < 3; ++kj) {
                        const float* w = &k2[((c * 3 + ki) * 3 + kj) * 9];
#pragma unroll
                        for (int p = 0; p < 2; ++p) {
                            float v = iv[p + kj];
#pragma unroll
                            for (int o = 0; o < 9; ++o)
                                acc[r][p][o] = fmaf(v, w[o], acc[r][p][o]);
                        }
                    }
                }
            }
        }

    // ---- relu; zero abs row/col 63 (pool pad) ----
#pragma unroll
    for (int r = 0; r < 2; ++r)
#pragma unroll
        for (int p = 0; p < 2; ++p)
#pragma unroll
            for (int o = 0; o < 9; ++o)
                acc[r][p][o] = fmaxf(acc[r][p][o], 0.f);
    if (px == 31) {
#pragma unroll
        for (int r = 0; r < 2; ++r)
#pragma unroll
            for (int o = 0; o < 9; ++o) acc[r][1][o] = 0.f;
    }
    if (py == 31) {
#pragma unroll
        for (int p = 0; p < 2; ++p)
#pragma unroll
            for (int o = 0; o < 9; ++o) acc[1][p][o] = 0.f;
    }

    // ---- halo ring, ch split 3/3/3 over threads 0..194 ----
    if (tid < 195) {
        const int grp = (tid >= 130) ? 2 : ((tid >= 65) ? 1 : 0);
        const int idx = tid - 65 * grp;
        int ryh, rxh;
        if (idx < 33) { ryh = -1; rxh = idx - 1; }
        else          { ryh = idx - 33; rxh = -1; }
        const int cy = 32 * ty + ryh, cx = 32 * tx + rxh;
        const bool ok = (unsigned)cy < 63u && (unsigned)cx < 63u;
        if      (grp == 0) conv2_halo<0, 3>(sIn, k2, ryh, rxh, ok, sH, idx);
        else if (grp == 1) conv2_halo<3, 3>(sIn, k2, ryh, rxh, ok, sH, idx);
        else               conv2_halo<6, 3>(sIn, k2, ryh, rxh, ok, sH, idx);
    }

    __syncthreads();                       // sIn reads complete -> alias ok

    float* sE0 = smem;                     // [5][256] per pass
    float* sE1 = smem + 5 * 256;
    float* sB  = smem + 10 * 256;
    const int tU  = (lpy > 0) ? tid - 16 : 0;
    const int tL  = (lpx > 0) ? tid - 1  : 0;
    const int tUL = (lpy > 0 && lpx > 0) ? tid - 17 : 0;

    // ---- pass 0: channels 0..4 ----
#pragma unroll
    for (int o = 0; o < 5; ++o) {
        sE0[o * 256 + tid] = acc[0][1][o];
        sE1[o * 256 + tid] = acc[1][1][o];
        sB [o * 256 + tid] = fmaxf(acc[1][0][o], acc[1][1][o]);
    }
    __syncthreads();
#pragma unroll
    for (int o = 0; o < 5; ++o) {
        float a0 = fmaxf(acc[0][0][o], acc[0][1][o]);
        float a1 = fmaxf(acc[1][0][o], acc[1][1][o]);
        float u  = (lpy > 0) ? sB[o * 256 + tU]
                             : fmaxf(sH[o][1 + 2 * lpx], sH[o][2 + 2 * lpx]);
        float l0 = (lpx > 0) ? sE0[o * 256 + tL] : sH[o][33 + 2 * lpy];
        float l1 = (lpx > 0) ? sE1[o * 256 + tL] : sH[o][34 + 2 * lpy];
        float ul = (lpy > 0 && lpx > 0) ? sE1[o * 256 + tUL]
                 : ((lpy == 0) ? sH[o][2 * lpx] : sH[o][32 + 2 * lpy]);
        float m = fmaxf(fmaxf(fmaxf(a0, a1), fmaxf(u, l0)), fmaxf(l1, ul));
        out2[((b * 9 + o) * 32 + py) * 32 + px] = m;
    }
    __syncthreads();

    // ---- pass 1: channels 5..8 ----
#pragma unroll
    for (int o = 5; o < 9; ++o) {
        sE0[(o - 5) * 256 + tid] = acc[0][1][o];
        sE1[(o - 5) * 256 + tid] = acc[1][1][o];
        sB [(o - 5) * 256 + tid] = fmaxf(acc[1][0][o], acc[1][1][o]);
    }
    __syncthreads();
#pragma unroll
    for (int o = 5; o < 9; ++o) {
        float a0 = fmaxf(acc[0][0][o], acc[0][1][o]);
        float a1 = fmaxf(acc[1][0][o], acc[1][1][o]);
        float u  = (lpy > 0) ? sB[(o - 5) * 256 + tU]
                             : fmaxf(sH[o][1 + 2 * lpx], sH[o][2 + 2 * lpx]);
        float l0 = (lpx > 0) ? sE0[(o - 5) * 256 + tL] : sH[o][33 + 2 * lpy];
        float l1 = (lpx > 0) ? sE1[(o - 5) * 256 + tL] : sH[o][34 + 2 * lpy];
        float ul = (lpy > 0 && lpx > 0) ? sE1[(o - 5) * 256 + tUL]
                 : ((lpy == 0) ? sH[o][2 * lpx] : sH[o][32 + 2 * lpy]);
        float m = fmaxf(fmaxf(fmaxf(a0, a1), fmaxf(u, l0)), fmaxf(l1, ul));
        out2[((b * 9 + o) * 32 + py) * 32 + px] = m;
    }
}

// ===========================================================================
// Stage 3: conv3(3x3,pad1) + flatten + FC(16384->6) + softmax, per sample.
//   1024 threads, one conv pixel each.
//   w(o,c,ki,kj) = k3[((c*3+ki)*3+kj)*16 + o]
// ===========================================================================
__global__ __launch_bounds__(1024) void conv3_fc_kernel(
    const float* __restrict__ in2, const float* __restrict__ k3,
    const float* __restrict__ fcw, const float* __restrict__ fcb,
    float* __restrict__ out)
{
    const int b   = blockIdx.x;
    const int tid = threadIdx.x;

    __shared__ float sP[9][34][36];   // zero-padded border
    __shared__ float sRed[16][6];

    for (int idx = tid; idx < 9 * 34 * 36; idx += 1024) {
        int c  = idx / (34 * 36);
        int r  = idx - c * (34 * 36);
        int yy = r / 36, xx = r - yy * 36;
        float v = 0.f;
        if (yy >= 1 && yy < 33 && xx >= 1 && xx < 33)
            v = in2[((b * 9 + c) * 32 + (yy - 1)) * 32 + (xx - 1)];
        sP[c][yy][xx] = v;
    }
    __syncthreads();

    const int s = tid;                 // spatial index 0..1023
    const int y = s >> 5, xc = s & 31;

    float acc16[16];
#pragma unroll
    for (int o = 0; o < 16; ++o) acc16[o] = 0.f;

#pragma unroll
    for (int c = 0; c < 9; ++c)
#pragma unroll
        for (int ki = 0; ki < 3; ++ki) {
            float iv[3];
#pragma unroll
            for (int j = 0; j < 3; ++j) iv[j] = sP[c][y + ki][xc + j];
#pragma unroll
            for (int kj = 0; kj < 3; ++kj) {
                float v = iv[kj];
                const float* w = &k3[((c * 3 + ki) * 3 + kj) * 16];
#pragma unroll
                for (int o = 0; o < 16; ++o)
                    acc16[o] = fmaf(v, w[o], acc16[o]);
            }
        }

    float acc6[6] = {0.f, 0.f, 0.f, 0.f, 0.f, 0.f};
#pragma unroll
    for (int o = 0; o < 16; ++o) {
        const int f = o * 1024 + s;
#pragma unroll
        for (int cls = 0; cls < 6; ++cls)
            acc6[cls] = fmaf(acc16[o], fcw[cls * 16384 + f], acc6[cls]);
    }

#pragma unroll
    for (int cls = 0; cls < 6; ++cls) {
        float v = acc6[cls];
#pragma unroll
        for (int off = 32; off >= 1; off >>= 1)
            v += __shfl_xor(v, off, 64);
        if ((tid & 63) == 0) sRed[tid >> 6][cls] = v;
    }
    __syncthreads();
    if (tid == 0) {
        float logits[6], mxl = -3.4e38f;
#pragma unroll
        for (int cls = 0; cls < 6; ++cls) {
            float l = fcb[cls];
            for (int wv = 0; wv < 16; ++wv) l += sRed[wv][cls];
            logits[cls] = l;
            mxl = fmaxf(mxl, l);
        }
        float ssum = 0.f;
#pragma unroll
        for (int cls = 0; cls < 6; ++cls) {
            logits[cls] = expf(logits[cls] - mxl);
            ssum += logits[cls];
        }
#pragma unroll
        for (int cls = 0; cls < 6; ++cls)
            out[b * 6 + cls] = logits[cls] / ssum;
    }
}

extern "C" void kernel_launch(void* const* d_in, const int* in_sizes, int n_in,
                              void* d_out, int out_size, void* d_ws, size_t ws_size,
                              hipStream_t stream)
{
    const float* x     = (const float*)d_in[0];
    const float* k1    = (const float*)d_in[1];
    const float* gamma = (const float*)d_in[2];
    const float* beta  = (const float*)d_in[3];
    const float* k2    = (const float*)d_in[4];
    const float* k3    = (const float*)d_in[5];
    const float* fcw   = (const float*)d_in[6];
    const float* fcb   = (const float*)d_in[7];
    float* out = (float*)d_out;

    float* out1 = (float*)d_ws;                       // 512*5*63*63  (40.6 MB)
    float* out2 = out1 + (size_t)512 * 5 * 63 * 63;   // 512*9*32*32  (18.9 MB)

    conv1_pool_kernel<<<dim3(16, 512), 256, 0, stream>>>(x, k1, gamma, beta, out1);
    conv2_pool_kernel<<<dim3(4, 512), 256, 0, stream>>>(out1, k2, out2);
    conv3_fc_kernel<<<dim3(512), 1024, 0, stream>>>(out2, k3, fcw, fcb, out);
}